// Round 1
// baseline (888.716 us; speedup 1.0000x reference)
//
#include <hip/hip_runtime.h>
#include <math.h>

#define Bsz 8
#define Nn 1024
#define CIN 256
#define COUT 256
#define NR 4
#define NH 4

// ws layout (floats):
//   f:   [NR][Bsz][Nn][COUT]          8,388,608 floats
//   LiD: [NR][Bsz][Nn][NH] float4       131,072 float4
//   LjD: [NR][Bsz][Nn][NH] float4       131,072 float4
#define F_ELEMS (NR * Bsz * Nn * COUT)
#define L_ELEMS (NR * Bsz * Nn * NH)

__device__ __forceinline__ void fma4(float4& A, float xv, const float4& w) {
  A.x = fmaf(xv, w.x, A.x);
  A.y = fmaf(xv, w.y, A.y);
  A.z = fmaf(xv, w.z, A.z);
  A.w = fmaf(xv, w.w, A.w);
}

// Kernel A: f[r][b][n][c] = X[b][n][:] @ W[r][:][c]; fused li/lj + exp tables.
// Grid 512 (16-row tiles of the 8192 global rows), block 256.
// Thread t owns cols 4t..4t+3 -> r = t>>6, head h = (t>>4)&3, c-base = (t&15)*4.
__global__ __launch_bounds__(256, 2)
void gatt_gemm(const float* __restrict__ X, const float* __restrict__ W,
               const float* __restrict__ a, float* __restrict__ f,
               float4* __restrict__ LiD, float4* __restrict__ LjD) {
  __shared__ float Xs[256 * 16];  // [k][il] transposed for broadcast reads
  const int t = threadIdx.x;
  const int row0 = blockIdx.x * 16;

#pragma unroll
  for (int il = 0; il < 16; ++il)
    Xs[t * 16 + il] = X[(size_t)(row0 + il) * CIN + t];
  __syncthreads();

  const int r = t >> 6;
  const int cc = (t & 63) * 4;
  const float* Wp = W + (size_t)r * CIN * COUT + cc;

  float4 acc[16];
#pragma unroll
  for (int il = 0; il < 16; ++il) acc[il] = make_float4(0.f, 0.f, 0.f, 0.f);

#pragma unroll 4
  for (int k = 0; k < CIN; ++k) {
    const float4 w4 = *(const float4*)(Wp + (size_t)k * COUT);
    const float4* xs = (const float4*)(Xs + k * 16);
#pragma unroll
    for (int q = 0; q < 4; ++q) {
      const float4 xq = xs[q];
      fma4(acc[q * 4 + 0], xq.x, w4);
      fma4(acc[q * 4 + 1], xq.y, w4);
      fma4(acc[q * 4 + 2], xq.z, w4);
      fma4(acc[q * 4 + 3], xq.w, w4);
    }
  }

  const int b = row0 >> 10;
  const int n0 = row0 & 1023;
#pragma unroll
  for (int il = 0; il < 16; ++il) {
    *(float4*)(f + ((size_t)(r * Bsz + b) * Nn + n0 + il) * COUT + cc) = acc[il];
  }

  // epilogue: li = f . a_l, lj = f . a_r per (row, r, h)
  const int h = (t >> 4) & 3;
  const int cb = (t & 15) * 4;
  const float4 al = *(const float4*)(a + r * NH * 128 + h * 128 + cb);
  const float4 ar = *(const float4*)(a + r * NH * 128 + h * 128 + 64 + cb);
#pragma unroll
  for (int il = 0; il < 16; ++il) {
    float lip = acc[il].x * al.x + acc[il].y * al.y + acc[il].z * al.z + acc[il].w * al.w;
    float ljp = acc[il].x * ar.x + acc[il].y * ar.y + acc[il].z * ar.z + acc[il].w * ar.w;
#pragma unroll
    for (int off = 8; off >= 1; off >>= 1) {
      lip += __shfl_down(lip, off, 16);
      ljp += __shfl_down(ljp, off, 16);
    }
    if ((t & 15) == 0) {
      const size_t idx = ((size_t)(r * Bsz + b) * Nn + n0 + il) * NH + h;
      LiD[idx] = make_float4(lip, expf(lip), expf(0.2f * lip), 0.f);
      LjD[idx] = make_float4(ljp, expf(ljp), expf(0.2f * ljp), 0.f);
    }
  }
}

// Kernel B: out[b,i,h*64+c] = sum_r ( sum_j w_r[i,j,h] f_r[j,h,c] ) / sum_j w_r[i,j,h]
// w = adj ? (li+lj>0 ? e^li e^lj : e^.2li e^.2lj) : 0   (exact unnormalized softmax)
// Grid 512: b = bid&7 (XCD swizzle so one XCD's blocks share b -> f L2-resident),
// itile = bid>>3 (16 i-rows). Block 256: phase1 thread = (il=t>>4, jb=t&15);
// phase2 thread = output col t (head myh = t>>6).
__global__ __launch_bounds__(256, 2)
void gatt_attn(const int* __restrict__ adj, const float* __restrict__ f,
               const float4* __restrict__ LiD, const float4* __restrict__ LjD,
               float* __restrict__ out) {
  __shared__ float wbuf[128 * 68];   // [jl][h*16+il], stride 68 (pad: banks + 16B align)
  __shared__ float4 ljbuf[128 * 5];  // [jl*5 + h], stride 5 breaks bank conflicts
  __shared__ float4 libuf[16 * 4];   // [il*4 + h]
  __shared__ float denbuf[16 * 4];   // [il*4 + h]

  const int t = threadIdx.x;
  const int b = blockIdx.x & 7;
  const int itile = blockIdx.x >> 3;
  const int i0 = itile * 16;
  const int il1 = t >> 4;  // phase1 row
  const int jb = t & 15;   // phase1 j-lane
  const int myh = t >> 6;  // phase2 head

  float outacc[16];
#pragma unroll
  for (int il = 0; il < 16; ++il) outacc[il] = 0.f;

  for (int r = 0; r < NR; ++r) {
    __syncthreads();  // previous r's denbuf readers done
    if (t < 64) {
      const float4* LiDp = LiD + ((size_t)(r * Bsz + b) * Nn + i0) * NH;
      libuf[t] = LiDp[t];
      denbuf[t] = 0.f;
    }
    __syncthreads();
    const float4 li0 = libuf[il1 * 4 + 0];
    const float4 li1 = libuf[il1 * 4 + 1];
    const float4 li2 = libuf[il1 * 4 + 2];
    const float4 li3 = libuf[il1 * 4 + 3];

    float acc[16];
#pragma unroll
    for (int il = 0; il < 16; ++il) acc[il] = 0.f;

    for (int chunk = 0; chunk < Nn / 128; ++chunk) {
      const int j0 = chunk * 128;
      // stage LjD chunk -> ljbuf (coalesced float4)
      {
        const float4* LjDp = LjD + ((size_t)(r * Bsz + b) * Nn + j0) * NH;
#pragma unroll
        for (int q = 0; q < 2; ++q) {
          const int idx = t + q * 256;
          ljbuf[(idx >> 2) * 5 + (idx & 3)] = LjDp[idx];
        }
      }
      __syncthreads();

      // phase1: compute w for (16 i) x (128 j) x (4 h), + row-sums
      {
        const int i = i0 + il1;
        const int* adjp = adj + ((size_t)(b * Nn + i) * Nn + j0) * NR + r;
        float ws0 = 0.f, ws1 = 0.f, ws2 = 0.f, ws3 = 0.f;
#pragma unroll
        for (int k = 0; k < 8; ++k) {
          const int jl = jb + k * 16;
          const int adjv = adjp[jl * NR];
          const float4 lj0 = ljbuf[jl * 5 + 0];
          const float4 lj1 = ljbuf[jl * 5 + 1];
          const float4 lj2 = ljbuf[jl * 5 + 2];
          const float4 lj3 = ljbuf[jl * 5 + 3];
          float w0 = (li0.x + lj0.x > 0.f) ? li0.y * lj0.y : li0.z * lj0.z;
          float w1 = (li1.x + lj1.x > 0.f) ? li1.y * lj1.y : li1.z * lj1.z;
          float w2 = (li2.x + lj2.x > 0.f) ? li2.y * lj2.y : li2.z * lj2.z;
          float w3 = (li3.x + lj3.x > 0.f) ? li3.y * lj3.y : li3.z * lj3.z;
          if (adjv == 0) { w0 = 0.f; w1 = 0.f; w2 = 0.f; w3 = 0.f; }
          wbuf[jl * 68 + 0 * 16 + il1] = w0;
          wbuf[jl * 68 + 1 * 16 + il1] = w1;
          wbuf[jl * 68 + 2 * 16 + il1] = w2;
          wbuf[jl * 68 + 3 * 16 + il1] = w3;
          ws0 += w0; ws1 += w1; ws2 += w2; ws3 += w3;
        }
#pragma unroll
        for (int off = 8; off >= 1; off >>= 1) {
          ws0 += __shfl_down(ws0, off, 16);
          ws1 += __shfl_down(ws1, off, 16);
          ws2 += __shfl_down(ws2, off, 16);
          ws3 += __shfl_down(ws3, off, 16);
        }
        if (jb == 0) {
          denbuf[il1 * 4 + 0] += ws0;
          denbuf[il1 * 4 + 1] += ws1;
          denbuf[il1 * 4 + 2] += ws2;
          denbuf[il1 * 4 + 3] += ws3;
        }
      }
      __syncthreads();

      // phase2: acc[il] += w[il][jl][myh] * f[r][b][j0+jl][t]
      {
        const float* fp = f + ((size_t)(r * Bsz + b) * Nn + j0) * COUT + t;
#pragma unroll 2
        for (int jl = 0; jl < 128; ++jl) {
          const float fv = fp[(size_t)jl * COUT];
          const float4* wv = (const float4*)(wbuf + jl * 68 + myh * 16);
          const float4 w0 = wv[0], w1 = wv[1], w2 = wv[2], w3 = wv[3];
          acc[0]  = fmaf(w0.x, fv, acc[0]);
          acc[1]  = fmaf(w0.y, fv, acc[1]);
          acc[2]  = fmaf(w0.z, fv, acc[2]);
          acc[3]  = fmaf(w0.w, fv, acc[3]);
          acc[4]  = fmaf(w1.x, fv, acc[4]);
          acc[5]  = fmaf(w1.y, fv, acc[5]);
          acc[6]  = fmaf(w1.z, fv, acc[6]);
          acc[7]  = fmaf(w1.w, fv, acc[7]);
          acc[8]  = fmaf(w2.x, fv, acc[8]);
          acc[9]  = fmaf(w2.y, fv, acc[9]);
          acc[10] = fmaf(w2.z, fv, acc[10]);
          acc[11] = fmaf(w2.w, fv, acc[11]);
          acc[12] = fmaf(w3.x, fv, acc[12]);
          acc[13] = fmaf(w3.y, fv, acc[13]);
          acc[14] = fmaf(w3.z, fv, acc[14]);
          acc[15] = fmaf(w3.w, fv, acc[15]);
        }
      }
      __syncthreads();
    }

    // normalize this relation's contribution and accumulate
#pragma unroll
    for (int il = 0; il < 16; ++il)
      outacc[il] += acc[il] / denbuf[il * 4 + myh];
  }

#pragma unroll
  for (int il = 0; il < 16; ++il)
    out[((size_t)(b * Nn) + i0 + il) * COUT + t] = outacc[il];
}

extern "C" void kernel_launch(void* const* d_in, const int* in_sizes, int n_in,
                              void* d_out, int out_size, void* d_ws, size_t ws_size,
                              hipStream_t stream) {
  const float* X = (const float*)d_in[0];
  const int* adj = (const int*)d_in[1];
  const float* W = (const float*)d_in[2];
  const float* a = (const float*)d_in[3];
  float* out = (float*)d_out;

  float* ws = (float*)d_ws;
  float* f = ws;
  float4* LiD = (float4*)(ws + F_ELEMS);
  float4* LjD = (float4*)(ws + F_ELEMS + 4 * L_ELEMS);

  gatt_gemm<<<dim3(512), dim3(256), 0, stream>>>(X, W, a, f, LiD, LjD);
  gatt_attn<<<dim3(512), dim3(256), 0, stream>>>(adj, f, LiD, LjD, out);
}

// Round 2
// 398.619 us; speedup vs baseline: 2.2295x; 2.2295x over previous
//
#include <hip/hip_runtime.h>
#include <math.h>

#define Bsz 8
#define Nn 1024
#define CIN 256
#define COUT 256
#define NR 4
#define NH 4

typedef __attribute__((ext_vector_type(8))) short bf16x8;
typedef __attribute__((ext_vector_type(4))) float f32x4;

// ws layout (bytes):
//   fT   : [NR][Bsz][COUT][Nn] bf16   16 MB   (f transposed: c-major, j innermost)
//   LiD  : [NR][Bsz][Nn][NH] float4    2 MB   (li, e^li, e^0.2li, 0)
//   LjD  : same                        2 MB
//   adjm : [Bsz][Nn][NR][16] uint64    4 MB   (bit j of word jw = adj[b][i][jw*64+j][r]!=0)
#define FT_BYTES (16u * 1024u * 1024u)
#define L_BYTES (2u * 1024u * 1024u)

__device__ __forceinline__ short f2bf(float x) {
  union { float f; unsigned u; } v; v.f = x;
  unsigned r = (v.u + 0x7FFFu + ((v.u >> 16) & 1u)) >> 16;
  return (short)r;
}

// ---------- adjacency pack: 4 ints (r=0..3) per (b,i,j) -> 4 ballot bits ----------
__global__ __launch_bounds__(256, 8)
void gatt_pack(const int4* __restrict__ adj4, unsigned long long* __restrict__ adjm) {
  const int t = threadIdx.x;
  const int wid = blockIdx.x * 4 + (t >> 6);
  const int lane = t & 63;
  const int jw = wid & 15;
  const int i = (wid >> 4) & 1023;
  const int b = wid >> 14;
  const int j = jw * 64 + lane;
  const int4 av = adj4[(size_t)(b * Nn + i) * Nn + j];
  const unsigned long long b0 = __ballot(av.x != 0);
  const unsigned long long b1 = __ballot(av.y != 0);
  const unsigned long long b2 = __ballot(av.z != 0);
  const unsigned long long b3 = __ballot(av.w != 0);
  if (lane < 4) {
    unsigned long long v = (lane == 0) ? b0 : (lane == 1) ? b1 : (lane == 2) ? b2 : b3;
    adjm[((size_t)((b * Nn + i) * NR + lane)) * 16 + jw] = v;
  }
}

// ---------- GEMM: one r per block, 16 rows, thread owns one output column ----------
// grid 2048 = rowtile(512) x r(4), block 256. acc[16] scalar -> ~40 VGPR, high occupancy.
__global__ __launch_bounds__(256, 4)
void gatt_gemm(const float* __restrict__ X, const float* __restrict__ W,
               const float* __restrict__ a, unsigned short* __restrict__ fT,
               float4* __restrict__ LiD, float4* __restrict__ LjD) {
  __shared__ float Xs[16 * 260];  // rows padded 256->260 to spread staging banks
  const int t = threadIdx.x;
  const int r = blockIdx.x & 3;
  const int row0 = (blockIdx.x >> 2) * 16;
  const int b = row0 >> 10, n0 = row0 & 1023;

  {  // stage 16 rows of X
    const int il = t >> 4, kq = t & 15;
    const float4* xp = (const float4*)(X + (size_t)(row0 + il) * CIN + kq * 16);
    float4* dst = (float4*)(Xs + il * 260 + kq * 16);
#pragma unroll
    for (int u = 0; u < 4; ++u) dst[u] = xp[u];
  }
  __syncthreads();

  const float* Wp = W + (size_t)r * CIN * COUT + t;  // column c = t
  float acc[16];
#pragma unroll
  for (int il = 0; il < 16; ++il) acc[il] = 0.f;

#pragma unroll 4
  for (int kw = 0; kw < 64; ++kw) {
    const float w0 = Wp[(size_t)(4 * kw + 0) * COUT];
    const float w1 = Wp[(size_t)(4 * kw + 1) * COUT];
    const float w2 = Wp[(size_t)(4 * kw + 2) * COUT];
    const float w3 = Wp[(size_t)(4 * kw + 3) * COUT];
#pragma unroll
    for (int il = 0; il < 16; ++il) {
      const float4 x4 = *(const float4*)(Xs + il * 260 + 4 * kw);  // broadcast
      acc[il] = fmaf(x4.x, w0, acc[il]);
      acc[il] = fmaf(x4.y, w1, acc[il]);
      acc[il] = fmaf(x4.z, w2, acc[il]);
      acc[il] = fmaf(x4.w, w3, acc[il]);
    }
  }

  // fT store: fT[r][b][c=t][n0..n0+15] bf16, 32B contiguous per thread
  {
    unsigned short pk[16];
#pragma unroll
    for (int il = 0; il < 16; ++il) pk[il] = (unsigned short)f2bf(acc[il]);
    unsigned short* fp = fT + ((size_t)((r * Bsz + b) * COUT + t)) * Nn + n0;
    *(int4*)(fp) = *(int4*)(pk);
    *(int4*)(fp + 8) = *(int4*)(pk + 8);
  }

  // li/lj epilogue: wave = head (t>>6), reduce over its 64 c-lanes
  const int h = t >> 6, cl = t & 63;
  const float alv = a[r * NH * 128 + h * 128 + cl];
  const float arv = a[r * NH * 128 + h * 128 + 64 + cl];
#pragma unroll
  for (int il = 0; il < 16; ++il) {
    float lip = acc[il] * alv;
    float ljp = acc[il] * arv;
#pragma unroll
    for (int off = 32; off >= 1; off >>= 1) {
      lip += __shfl_down(lip, off);
      ljp += __shfl_down(ljp, off);
    }
    if (cl == 0) {
      const size_t idx = ((size_t)(r * Bsz + b) * Nn + n0 + il) * NH + h;
      LiD[idx] = make_float4(lip, expf(lip), expf(0.2f * lip), 0.f);
      LjD[idx] = make_float4(ljp, expf(ljp), expf(0.2f * ljp), 0.f);
    }
  }
}

// ---------- attention: MFMA flash-style, one r per block ----------
// grid 1024: bid&31 = (b,r) [XCD L2 locality], bid>>5 = itile (32 rows).
// block 512 = 8 waves: wave w -> head h=w&3, i-half ih=w>>2 (16 rows each).
// Per wave: A-frag = w-matrix computed in-lane (A[m=lane&15][k=quad*8+q]),
// B-frag = fT from LDS (j-contiguous), 4 n-tiles of 16 -> out[16x64] per head.
__global__ __launch_bounds__(512, 4)
void gatt_attn(const unsigned long long* __restrict__ adjm,
               const unsigned short* __restrict__ fT,
               const float4* __restrict__ LiD, const float4* __restrict__ LjD,
               float* __restrict__ out) {
  __shared__ unsigned short fTl[256 * 72];  // [c][64 j], row stride 72 (16B-aligned, even banks)
  __shared__ float4 ljb[4 * 64];            // [h][j] (ljx, e^lj, e^0.2lj, -)

  const int t = threadIdx.x;
  const int comb = blockIdx.x & 31;
  const int b = comb >> 2, r = comb & 3;
  const int i0 = (blockIdx.x >> 5) * 32;
  const int w = t >> 6, lane = t & 63;
  const int h = w & 3, ih = w >> 2;
  const int iw0 = i0 + ih * 16;
  const int m = lane & 15, quad = lane >> 4;
  const int i = iw0 + m;

  const float4 liv = LiD[((size_t)(r * Bsz + b) * Nn + i) * NH + h];
  const unsigned long long* amp = adjm + ((size_t)((b * Nn + i) * NR + r)) * 16;
  const size_t fTbase = (size_t)(r * Bsz + b) * COUT * Nn;

  f32x4 acc[4];
#pragma unroll
  for (int nt = 0; nt < 4; ++nt) acc[nt] = (f32x4){0.f, 0.f, 0.f, 0.f};
  float den = 0.f;

  for (int jc = 0; jc < Nn; jc += 64) {
    __syncthreads();  // prev chunk readers done
    {  // stage fT chunk: 256 c x 64 j bf16 = 32KB, 4 int4 per thread
#pragma unroll
      for (int k = 0; k < 4; ++k) {
        const int idx = k * 512 + t;
        const int c = idx >> 3, wd = idx & 7;
        const int4 v = *(const int4*)(fT + fTbase + (size_t)c * Nn + jc + wd * 8);
        *(int4*)(fTl + c * 72 + wd * 8) = v;
      }
    }
    if (t < 256) {  // stage LjD chunk
      const int hh = t >> 6, j = t & 63;
      ljb[hh * 64 + j] = LjD[((size_t)(r * Bsz + b) * Nn + jc + j) * NH + hh];
    }
    __syncthreads();

    const unsigned long long mask = amp[jc >> 6];
#pragma unroll
    for (int js = 0; js < 64; js += 32) {
      const unsigned mb = (unsigned)(mask >> (js + quad * 8)) & 0xFFu;
      bf16x8 af;
      float dsum = 0.f;
#pragma unroll
      for (int q = 0; q < 8; ++q) {
        const float4 lj = ljb[h * 64 + js + quad * 8 + q];
        const bool pos = (liv.x + lj.x) > 0.f;
        const float ea = pos ? liv.y : liv.z;
        const float eb = pos ? lj.y : lj.z;
        const float wv = ((mb >> q) & 1u) ? ea * eb : 0.f;
        dsum += wv;
        af[q] = f2bf(wv);
      }
      den += dsum;
#pragma unroll
      for (int nt = 0; nt < 4; ++nt) {
        const bf16x8 bf =
            *(const bf16x8*)(fTl + (h * 64 + nt * 16 + m) * 72 + js + quad * 8);
        acc[nt] = __builtin_amdgcn_mfma_f32_16x16x32_bf16(af, bf, acc[nt], 0, 0, 0);
      }
    }
  }

  // full denominator per i (lane's m): sum the 4 quad partials
  den += __shfl_xor(den, 16);
  den += __shfl_xor(den, 32);
  const float inv = 1.0f / den;

#pragma unroll
  for (int p = 0; p < 4; ++p) {
    const int row = quad * 4 + p;
    const float invp = __shfl(inv, quad * 4 + p);  // den lives at lane==i-offset
    float* op = out + ((size_t)(b * Nn) + iw0 + row) * COUT + h * 64 + m;
#pragma unroll
    for (int nt = 0; nt < 4; ++nt) atomicAdd(op + nt * 16, acc[nt][p] * invp);
  }
}

extern "C" void kernel_launch(void* const* d_in, const int* in_sizes, int n_in,
                              void* d_out, int out_size, void* d_ws, size_t ws_size,
                              hipStream_t stream) {
  const float* X = (const float*)d_in[0];
  const int4* adj4 = (const int4*)d_in[1];
  const float* W = (const float*)d_in[2];
  const float* a = (const float*)d_in[3];
  float* out = (float*)d_out;

  char* ws = (char*)d_ws;
  unsigned short* fT = (unsigned short*)ws;
  float4* LiD = (float4*)(ws + FT_BYTES);
  float4* LjD = (float4*)(ws + FT_BYTES + L_BYTES);
  unsigned long long* adjm = (unsigned long long*)(ws + FT_BYTES + 2 * L_BYTES);

  hipMemsetAsync(d_out, 0, (size_t)out_size * sizeof(float), stream);
  gatt_pack<<<dim3(32768), dim3(256), 0, stream>>>(adj4, adjm);
  gatt_gemm<<<dim3(2048), dim3(256), 0, stream>>>(X, W, a, fT, LiD, LjD);
  gatt_attn<<<dim3(1024), dim3(512), 0, stream>>>(adjm, fT, LiD, LjD, out);
}

// Round 3
// 373.615 us; speedup vs baseline: 2.3787x; 1.0669x over previous
//
#include <hip/hip_runtime.h>
#include <math.h>

#define Bsz 8
#define Nn 1024
#define CIN 256
#define COUT 256
#define NR 4
#define NH 4

typedef unsigned short u16;
typedef __attribute__((ext_vector_type(8))) short bf16x8;
typedef __attribute__((ext_vector_type(4))) float f32x4;

// ws layout (bytes):
//   fT   : [NR][Bsz][COUT][Nn] bf16          16 MB @ 0
//   LiDh : [NR*NH][Bsz][Nn] float4 (li,e^li,e^.2li,0)   2 MB @ 16M
//   LjDh : same                               2 MB @ 18M
//   adjm : [Bsz][Nn][NR][16] uint64           4 MB @ 20M
//   Xbf  : [Bsz*Nn][CIN] bf16                 4 MB @ 24M
//   WbfT : [NR][COUT][CIN] bf16 (transposed)  512K @ 28M
//   wa_l : [NR*NH][CIN] f32                   16K  @ 28M+512K
//   wa_r : [NR*NH][CIN] f32                   16K  @ +16K
#define OFF_LIDH (16u << 20)
#define OFF_LJDH (18u << 20)
#define OFF_ADJM (20u << 20)
#define OFF_XBF (24u << 20)
#define OFF_WBFT (28u << 20)
#define OFF_WAL ((28u << 20) + (512u << 10))
#define OFF_WAR ((28u << 20) + (528u << 10))

__device__ __forceinline__ short f2bf(float x) {
  union { float f; unsigned u; } v; v.f = x;
  unsigned r = (v.u + 0x7FFFu + ((v.u >> 16) & 1u)) >> 16;
  return (short)r;
}

// async global->LDS, 16B per lane; dest = wave-uniform base + lane*16
__device__ __forceinline__ void gl_lds16(const void* g, void* l) {
  __builtin_amdgcn_global_load_lds(
      (const __attribute__((address_space(1))) unsigned int*)(unsigned long long)g,
      (__attribute__((address_space(3))) unsigned int*)(unsigned int)(unsigned long long)l,
      16, 0, 0);
}

// ---------- adjacency pack ----------
__global__ __launch_bounds__(256, 8)
void gatt_pack(const int4* __restrict__ adj4, unsigned long long* __restrict__ adjm) {
  const int t = threadIdx.x;
  const int wid = blockIdx.x * 4 + (t >> 6);
  const int lane = t & 63;
  const int jw = wid & 15;
  const int i = (wid >> 4) & 1023;
  const int b = wid >> 14;
  const int j = jw * 64 + lane;
  const int4 av = adj4[(size_t)(b * Nn + i) * Nn + j];
  const unsigned long long b0 = __ballot(av.x != 0);
  const unsigned long long b1 = __ballot(av.y != 0);
  const unsigned long long b2 = __ballot(av.z != 0);
  const unsigned long long b3 = __ballot(av.w != 0);
  if (lane < 4) {
    unsigned long long v = (lane == 0) ? b0 : (lane == 1) ? b1 : (lane == 2) ? b2 : b3;
    adjm[((size_t)((b * Nn + i) * NR + lane)) * 16 + jw] = v;
  }
}

// ---------- X -> bf16 ----------
__global__ __launch_bounds__(256, 8)
void gatt_xconv(const float4* __restrict__ X4, int4* __restrict__ Xbf4) {
  const int idx = blockIdx.x * 256 + threadIdx.x;  // one per 8 floats
  const float4 a = X4[idx * 2], b = X4[idx * 2 + 1];
  u16 pk[8];
  pk[0] = (u16)f2bf(a.x); pk[1] = (u16)f2bf(a.y); pk[2] = (u16)f2bf(a.z); pk[3] = (u16)f2bf(a.w);
  pk[4] = (u16)f2bf(b.x); pk[5] = (u16)f2bf(b.y); pk[6] = (u16)f2bf(b.z); pk[7] = (u16)f2bf(b.w);
  Xbf4[idx] = *(int4*)pk;
}

// ---------- W -> bf16 transposed: WbfT[r][c][k] ----------
__global__ __launch_bounds__(256, 4)
void gatt_wtrans(const float* __restrict__ W, u16* __restrict__ WbfT) {
  const int t = threadIdx.x;                 // c
  const int r = blockIdx.x >> 3, kc = blockIdx.x & 7;
  u16 pk[32];
#pragma unroll 8
  for (int kk = 0; kk < 32; ++kk)
    pk[kk] = (u16)f2bf(W[(size_t)r * 65536 + (size_t)(kc * 32 + kk) * COUT + t]);
  u16* dst = WbfT + (size_t)r * 65536 + (size_t)t * CIN + kc * 32;
#pragma unroll
  for (int q = 0; q < 4; ++q) *(int4*)(dst + q * 8) = *(int4*)(pk + q * 8);
}

// ---------- wa[r][h][k] = sum_c W[r][k][h*64+c] * a[r][h][c] ----------
__global__ __launch_bounds__(256, 4)
void gatt_wa(const float* __restrict__ W, const float* __restrict__ a,
             float* __restrict__ wa_l, float* __restrict__ wa_r) {
  const int t = threadIdx.x;  // k
  const int r = blockIdx.x >> 2, h = blockIdx.x & 3;
  float sl = 0.f, sr = 0.f;
  const float* Wp = W + (size_t)r * 65536 + (size_t)t * COUT + h * 64;
  const float* ap = a + r * 512 + h * 128;
#pragma unroll 8
  for (int c = 0; c < 64; ++c) {
    const float wv = Wp[c];
    sl = fmaf(wv, ap[c], sl);
    sr = fmaf(wv, ap[64 + c], sr);
  }
  wa_l[(size_t)blockIdx.x * CIN + t] = sl;
  wa_r[(size_t)blockIdx.x * CIN + t] = sr;
}

// ---------- logits: li = X . wa_l, lj = X . wa_r (fp32), + exp tables ----------
// grid 512 (16 rows), block 256 = 16 rows x 16 (r,h) combos
__global__ __launch_bounds__(256, 4)
void gatt_logit(const float* __restrict__ X, const float4* __restrict__ wal4,
                const float4* __restrict__ war4, float4* __restrict__ LiDh,
                float4* __restrict__ LjDh) {
  __shared__ float Xs[16 * 260];
  const int t = threadIdx.x;
  const int row0 = blockIdx.x * 16;
  {
    const int il = t >> 4, kq = t & 15;
    const float4* xp = (const float4*)(X + (size_t)(row0 + il) * CIN + kq * 16);
    float4* dst = (float4*)(Xs + il * 260 + kq * 16);
#pragma unroll
    for (int u = 0; u < 4; ++u) dst[u] = xp[u];
  }
  __syncthreads();
  const int rl = t >> 4, combo = t & 15;
  float li = 0.f, lj = 0.f;
#pragma unroll 8
  for (int k4 = 0; k4 < 64; ++k4) {
    const float4 x4 = *(const float4*)(Xs + rl * 260 + k4 * 4);
    const float4 wl = wal4[combo * 64 + k4];
    const float4 wr = war4[combo * 64 + k4];
    li += x4.x * wl.x + x4.y * wl.y + x4.z * wl.z + x4.w * wl.w;
    lj += x4.x * wr.x + x4.y * wr.y + x4.z * wr.z + x4.w * wr.w;
  }
  const int g = row0 + rl, b = g >> 10, n = g & 1023;
  const size_t idx = ((size_t)(combo * Bsz + b)) * Nn + n;
  LiDh[idx] = make_float4(li, expf(li), expf(0.2f * li), 0.f);
  LjDh[idx] = make_float4(lj, expf(lj), expf(0.2f * lj), 0.f);
}

// ---------- f GEMM via MFMA: fT[r][b][c][n] = sum_k W[k][c]*X[n][k] ----------
// grid 512: bid&3=r, (bid>>2)&7=b, bid>>5=ntile(64 n). block 256 = 4 waves,
// wave = c-quarter (64 c). K=256 in 8 chunks of 32. XOR-swizzled LDS.
__global__ __launch_bounds__(256)
void gatt_fgemm(const u16* __restrict__ Xbf, const u16* __restrict__ WbfT,
                u16* __restrict__ fT) {
  __shared__ u16 lds_w[8192];  // [256 c][32 k], 16B slots XOR'd by c&3
  __shared__ u16 lds_x[2048];  // [64 n][32 k]
  const int t = threadIdx.x;
  const int r = blockIdx.x & 3, b = (blockIdx.x >> 2) & 7, ntl = blockIdx.x >> 5;
  const int n0 = ntl * 64;
  const int g0 = b * Nn + n0;
  const int lane = t & 63, w = t >> 6;
  const int m = lane & 15, quad = lane >> 4;
  const int cw = w * 64;
  const int xq = quad ^ (m & 3);

  const u16* Wsrc = WbfT + (size_t)r * 65536;
  f32x4 acc[4][4];
#pragma unroll
  for (int ct = 0; ct < 4; ++ct)
#pragma unroll
    for (int nt = 0; nt < 4; ++nt) acc[ct][nt] = (f32x4){0.f, 0.f, 0.f, 0.f};

  for (int kc = 0; kc < 8; ++kc) {
    __syncthreads();
#pragma unroll
    for (int q = 0; q < 4; ++q) {  // stage W chunk: 1024 slots
      const int s = q * 256 + t;
      const int c = s >> 2, ks = (s & 3) ^ (c & 3);
      gl_lds16(Wsrc + (size_t)c * CIN + kc * 32 + ks * 8, lds_w + s * 8);
    }
    {  // stage X chunk: 256 slots
      const int s = t;
      const int n = s >> 2, ks = (s & 3) ^ (n & 3);
      gl_lds16(Xbf + (size_t)(g0 + n) * CIN + kc * 32 + ks * 8, lds_x + s * 8);
    }
    __syncthreads();

    bf16x8 af[4], bfr[4];
#pragma unroll
    for (int ct = 0; ct < 4; ++ct)
      af[ct] = *(const bf16x8*)(lds_w + (cw + ct * 16 + m) * 32 + xq * 8);
#pragma unroll
    for (int nt = 0; nt < 4; ++nt)
      bfr[nt] = *(const bf16x8*)(lds_x + (nt * 16 + m) * 32 + xq * 8);
#pragma unroll
    for (int ct = 0; ct < 4; ++ct)
#pragma unroll
      for (int nt = 0; nt < 4; ++nt)
        acc[ct][nt] = __builtin_amdgcn_mfma_f32_16x16x32_bf16(af[ct], bfr[nt], acc[ct][nt], 0, 0, 0);
  }

  u16* fbase = fT + ((size_t)(r * Bsz + b) * COUT) * Nn;
#pragma unroll
  for (int ct = 0; ct < 4; ++ct) {
#pragma unroll
    for (int p = 0; p < 4; ++p) {
      const int c = cw + ct * 16 + quad * 4 + p;
      u16* op = fbase + (size_t)c * Nn + n0 + m;
#pragma unroll
      for (int nt = 0; nt < 4; ++nt) op[nt * 16] = (u16)f2bf(acc[ct][nt][p]);
    }
  }
}

// ---------- attention ----------
// grid 1024: bid&31=(b,r) XCD swizzle, bid>>5 = itile(32 rows). block 512 =
// 8 waves = 4 heads x 2 i-halves. fT chunk staged via global_load_lds with
// XOR(c&7) swizzle (bank-uniform b128 frag reads); lj read from global (L1).
__global__ __launch_bounds__(512, 6)
void gatt_attn(const unsigned long long* __restrict__ adjm,
               const u16* __restrict__ fT, const float4* __restrict__ LiDh,
               const float4* __restrict__ LjDh, float* __restrict__ out) {
  __shared__ u16 fTl[16384];  // 2048 x 16B slots: [c][8 jg], jg-slot XOR c&7

  const int t = threadIdx.x;
  const int comb = blockIdx.x & 31;
  const int b = comb >> 2, r = comb & 3;
  const int i0 = (blockIdx.x >> 5) * 32;
  const int w = t >> 6, lane = t & 63;
  const int h = w & 3, ih = w >> 2;
  const int iw0 = i0 + ih * 16;
  const int m = lane & 15, quad = lane >> 4;
  const int i = iw0 + m;
  const int xq0 = quad ^ (m & 7);
  const int cb = h * 64 + m;

  const float4 liv = LiDh[((size_t)((r * NH + h) * Bsz + b)) * Nn + i];
  const float4* ljbase = LjDh + ((size_t)((r * NH + h) * Bsz + b)) * Nn + quad * 8;
  const unsigned long long* amp = adjm + ((size_t)((b * Nn + i) * NR + r)) * 16;
  const size_t fTbase = (size_t)(r * Bsz + b) * COUT * Nn;

  f32x4 acc[4];
#pragma unroll
  for (int nt = 0; nt < 4; ++nt) acc[nt] = (f32x4){0.f, 0.f, 0.f, 0.f};
  float den = 0.f;

  for (int jc = 0; jc < Nn; jc += 64) {
    __syncthreads();
#pragma unroll
    for (int p = 0; p < 4; ++p) {  // stage 2048 slots (32KB)
      const int s = p * 512 + t;
      const int c = s >> 3, jg = (s & 7) ^ (c & 7);
      gl_lds16(fT + fTbase + (size_t)c * Nn + jc + jg * 8, fTl + s * 8);
    }
    __syncthreads();

    const unsigned long long mask = amp[jc >> 6];
    const float4* ljc = ljbase + jc;
#pragma unroll
    for (int js = 0; js < 2; ++js) {
      const unsigned mb = (unsigned)(mask >> (js * 32 + quad * 8)) & 0xFFu;
      const float4* ljp = ljc + js * 32;
      bf16x8 af;
      float dsum = 0.f;
#pragma unroll
      for (int q = 0; q < 8; ++q) {
        const float4 lj = ljp[q];
        const bool pos = (liv.x + lj.x) > 0.f;
        const float wv = ((mb >> q) & 1u) ? (pos ? liv.y : liv.z) * (pos ? lj.y : lj.z) : 0.f;
        dsum += wv;
        af[q] = f2bf(wv);
      }
      den += dsum;
      const int xq = xq0 ^ (js << 2);
#pragma unroll
      for (int nt = 0; nt < 4; ++nt) {
        const bf16x8 bfv = *(const bf16x8*)(fTl + (cb + nt * 16) * 64 + xq * 8);
        acc[nt] = __builtin_amdgcn_mfma_f32_16x16x32_bf16(af, bfv, acc[nt], 0, 0, 0);
      }
    }
  }

  den += __shfl_xor(den, 16);
  den += __shfl_xor(den, 32);
  const float inv = 1.0f / den;

#pragma unroll
  for (int p = 0; p < 4; ++p) {
    const int row = quad * 4 + p;
    const float invp = __shfl(inv, quad * 4 + p);
    float* op = out + ((size_t)(b * Nn) + iw0 + row) * COUT + h * 64 + m;
#pragma unroll
    for (int nt = 0; nt < 4; ++nt) atomicAdd(op + nt * 16, acc[nt][p] * invp);
  }
}

extern "C" void kernel_launch(void* const* d_in, const int* in_sizes, int n_in,
                              void* d_out, int out_size, void* d_ws, size_t ws_size,
                              hipStream_t stream) {
  const float* X = (const float*)d_in[0];
  const int4* adj4 = (const int4*)d_in[1];
  const float* W = (const float*)d_in[2];
  const float* a = (const float*)d_in[3];
  float* out = (float*)d_out;

  char* ws = (char*)d_ws;
  u16* fT = (u16*)ws;
  float4* LiDh = (float4*)(ws + OFF_LIDH);
  float4* LjDh = (float4*)(ws + OFF_LJDH);
  unsigned long long* adjm = (unsigned long long*)(ws + OFF_ADJM);
  u16* Xbf = (u16*)(ws + OFF_XBF);
  u16* WbfT = (u16*)(ws + OFF_WBFT);
  float* wa_l = (float*)(ws + OFF_WAL);
  float* wa_r = (float*)(ws + OFF_WAR);

  hipMemsetAsync(d_out, 0, (size_t)out_size * sizeof(float), stream);
  gatt_pack<<<dim3(32768), dim3(256), 0, stream>>>(adj4, adjm);
  gatt_xconv<<<dim3(1024), dim3(256), 0, stream>>>((const float4*)X, (int4*)Xbf);
  gatt_wtrans<<<dim3(32), dim3(256), 0, stream>>>(W, WbfT);
  gatt_wa<<<dim3(16), dim3(256), 0, stream>>>(W, a, wa_l, wa_r);
  gatt_logit<<<dim3(512), dim3(256), 0, stream>>>(X, (const float4*)wa_l,
                                                  (const float4*)wa_r, LiDh, LjDh);
  gatt_fgemm<<<dim3(512), dim3(256), 0, stream>>>(Xbf, WbfT, fT);
  gatt_attn<<<dim3(1024), dim3(512), 0, stream>>>(adjm, fT, LiDh, LjDh, out);
}

// Round 4
// 308.954 us; speedup vs baseline: 2.8765x; 1.2093x over previous
//
#include <hip/hip_runtime.h>
#include <math.h>

#define Bsz 8
#define Nn 1024
#define CIN 256
#define COUT 256
#define NR 4
#define NH 4

typedef unsigned short u16;
typedef __attribute__((ext_vector_type(8))) short bf16x8;
typedef __attribute__((ext_vector_type(4))) float f32x4;

// ws layout (bytes):
//   fTf  : [sl=r*8+b][h][jb 0..31][nt 0..3][lane 0..63] bf16x8  16 MB @ 0
//          (MFMA B-frag order: lane qt*16+mt holds rows c=h*64+nt*16+mt,
//           cols j=jb*32+qt*8+e, e=0..7)
//   Lip  : [combo=r*4+h][b][n] f32 (li*log2e)   512K @ 16M
//   Ljp  : same                                  512K @ 16.5M
//   adjm : [b][i][r][16] u64                     4 MB @ 17M
//   Xbf  : [b*n][k] bf16                         4 MB @ 21M
//   WbfT : [r][c][k] bf16                        512K @ 25M
//   wa_l : [combo][k] f32                        16K  @ 25.5M
//   wa_r : [combo][k] f32                        16K  @ +16K
#define OFF_LIP (16u << 20)
#define OFF_LJP ((16u << 20) + (512u << 10))
#define OFF_ADJM (17u << 20)
#define OFF_XBF (21u << 20)
#define OFF_WBFT (25u << 20)
#define OFF_WAL ((25u << 20) + (512u << 10))
#define OFF_WAR ((25u << 20) + (528u << 10))

#define LOG2E 1.4426950408889634f

__device__ __forceinline__ short f2bf(float x) {
  union { float f; unsigned u; } v; v.f = x;
  unsigned r = (v.u + 0x7FFFu + ((v.u >> 16) & 1u)) >> 16;
  return (short)r;
}

__device__ __forceinline__ float fast_exp2(float x) {
#if __has_builtin(__builtin_amdgcn_exp2f)
  return __builtin_amdgcn_exp2f(x);
#else
  return exp2f(x);
#endif
}

// async global->LDS, 16B per lane
__device__ __forceinline__ void gl_lds16(const void* g, void* l) {
  __builtin_amdgcn_global_load_lds(
      (const __attribute__((address_space(1))) unsigned int*)(unsigned long long)g,
      (__attribute__((address_space(3))) unsigned int*)(unsigned int)(unsigned long long)l,
      16, 0, 0);
}

// ---------- adjacency pack ----------
__global__ __launch_bounds__(256, 8)
void gatt_pack(const int4* __restrict__ adj4, unsigned long long* __restrict__ adjm) {
  const int t = threadIdx.x;
  const int wid = blockIdx.x * 4 + (t >> 6);
  const int lane = t & 63;
  const int jw = wid & 15;
  const int i = (wid >> 4) & 1023;
  const int b = wid >> 14;
  const int j = jw * 64 + lane;
  const int4 av = adj4[(size_t)(b * Nn + i) * Nn + j];
  const unsigned long long b0 = __ballot(av.x != 0);
  const unsigned long long b1 = __ballot(av.y != 0);
  const unsigned long long b2 = __ballot(av.z != 0);
  const unsigned long long b3 = __ballot(av.w != 0);
  if (lane < 4) {
    unsigned long long v = (lane == 0) ? b0 : (lane == 1) ? b1 : (lane == 2) ? b2 : b3;
    adjm[((size_t)((b * Nn + i) * NR + lane)) * 16 + jw] = v;
  }
}

// ---------- X -> bf16 ----------
__global__ __launch_bounds__(256, 8)
void gatt_xconv(const float4* __restrict__ X4, int4* __restrict__ Xbf4) {
  const int idx = blockIdx.x * 256 + threadIdx.x;
  const float4 a = X4[idx * 2], b = X4[idx * 2 + 1];
  u16 pk[8];
  pk[0] = (u16)f2bf(a.x); pk[1] = (u16)f2bf(a.y); pk[2] = (u16)f2bf(a.z); pk[3] = (u16)f2bf(a.w);
  pk[4] = (u16)f2bf(b.x); pk[5] = (u16)f2bf(b.y); pk[6] = (u16)f2bf(b.z); pk[7] = (u16)f2bf(b.w);
  Xbf4[idx] = *(int4*)pk;
}

// ---------- W -> bf16 transposed ----------
__global__ __launch_bounds__(256, 4)
void gatt_wtrans(const float* __restrict__ W, u16* __restrict__ WbfT) {
  const int t = threadIdx.x;
  const int r = blockIdx.x >> 3, kc = blockIdx.x & 7;
  u16 pk[32];
#pragma unroll 8
  for (int kk = 0; kk < 32; ++kk)
    pk[kk] = (u16)f2bf(W[(size_t)r * 65536 + (size_t)(kc * 32 + kk) * COUT + t]);
  u16* dst = WbfT + (size_t)r * 65536 + (size_t)t * CIN + kc * 32;
#pragma unroll
  for (int q = 0; q < 4; ++q) *(int4*)(dst + q * 8) = *(int4*)(pk + q * 8);
}

// ---------- wa[r][h][k] = sum_c W[r][k][h*64+c] * a[r][h][c] ----------
__global__ __launch_bounds__(256, 4)
void gatt_wa(const float* __restrict__ W, const float* __restrict__ a,
             float* __restrict__ wa_l, float* __restrict__ wa_r) {
  const int t = threadIdx.x;  // k
  const int r = blockIdx.x >> 2, h = blockIdx.x & 3;
  float sl = 0.f, sr = 0.f;
  const float* Wp = W + (size_t)r * 65536 + (size_t)t * COUT + h * 64;
  const float* ap = a + r * 512 + h * 128;
#pragma unroll 8
  for (int c = 0; c < 64; ++c) {
    const float wv = Wp[c];
    sl = fmaf(wv, ap[c], sl);
    sr = fmaf(wv, ap[64 + c], sr);
  }
  wa_l[(size_t)blockIdx.x * CIN + t] = sl;
  wa_r[(size_t)blockIdx.x * CIN + t] = sr;
}

// ---------- logits (fp32, pre-scaled by log2e) ----------
__global__ __launch_bounds__(256, 4)
void gatt_logit(const float* __restrict__ X, const float4* __restrict__ wal4,
                const float4* __restrict__ war4, float* __restrict__ Lip,
                float* __restrict__ Ljp) {
  __shared__ float Xs[16 * 260];
  const int t = threadIdx.x;
  const int row0 = blockIdx.x * 16;
  {
    const int il = t >> 4, kq = t & 15;
    const float4* xp = (const float4*)(X + (size_t)(row0 + il) * CIN + kq * 16);
    float4* dst = (float4*)(Xs + il * 260 + kq * 16);
#pragma unroll
    for (int u = 0; u < 4; ++u) dst[u] = xp[u];
  }
  __syncthreads();
  const int rl = t >> 4, combo = t & 15;
  float li = 0.f, lj = 0.f;
#pragma unroll 8
  for (int k4 = 0; k4 < 64; ++k4) {
    const float4 x4 = *(const float4*)(Xs + rl * 260 + k4 * 4);
    const float4 wl = wal4[combo * 64 + k4];
    const float4 wr = war4[combo * 64 + k4];
    li += x4.x * wl.x + x4.y * wl.y + x4.z * wl.z + x4.w * wl.w;
    lj += x4.x * wr.x + x4.y * wr.y + x4.z * wr.z + x4.w * wr.w;
  }
  const int g = row0 + rl, b = g >> 10, n = g & 1023;
  const size_t idx = ((size_t)(combo * Bsz + b)) * Nn + n;
  Lip[idx] = li * LOG2E;
  Ljp[idx] = lj * LOG2E;
}

// ---------- f GEMM via MFMA, frag-ordered output ----------
__global__ __launch_bounds__(256)
void gatt_fgemm(const u16* __restrict__ Xbf, const u16* __restrict__ WbfT,
                u16* __restrict__ fTf) {
  __shared__ u16 lds_w[8192];
  __shared__ u16 lds_x[2048];
  const int t = threadIdx.x;
  const int r = blockIdx.x & 3, b = (blockIdx.x >> 2) & 7, ntl = blockIdx.x >> 5;
  const int n0 = ntl * 64;
  const int g0 = b * Nn + n0;
  const int lane = t & 63, w = t >> 6;
  const int m = lane & 15, quad = lane >> 4;
  const int cw = w * 64;
  const int xq = quad ^ (m & 3);

  const u16* Wsrc = WbfT + (size_t)r * 65536;
  f32x4 acc[4][4];
#pragma unroll
  for (int ct = 0; ct < 4; ++ct)
#pragma unroll
    for (int nt = 0; nt < 4; ++nt) acc[ct][nt] = (f32x4){0.f, 0.f, 0.f, 0.f};

  for (int kc = 0; kc < 8; ++kc) {
    __syncthreads();
#pragma unroll
    for (int q = 0; q < 4; ++q) {
      const int s = q * 256 + t;
      const int c = s >> 2, ks = (s & 3) ^ (c & 3);
      gl_lds16(Wsrc + (size_t)c * CIN + kc * 32 + ks * 8, lds_w + s * 8);
    }
    {
      const int s = t;
      const int n = s >> 2, ks = (s & 3) ^ (n & 3);
      gl_lds16(Xbf + (size_t)(g0 + n) * CIN + kc * 32 + ks * 8, lds_x + s * 8);
    }
    __syncthreads();

    bf16x8 af[4], bfr[4];
#pragma unroll
    for (int ct = 0; ct < 4; ++ct)
      af[ct] = *(const bf16x8*)(lds_w + (cw + ct * 16 + m) * 32 + xq * 8);
#pragma unroll
    for (int nt = 0; nt < 4; ++nt)
      bfr[nt] = *(const bf16x8*)(lds_x + (nt * 16 + m) * 32 + xq * 8);
#pragma unroll
    for (int ct = 0; ct < 4; ++ct)
#pragma unroll
      for (int nt = 0; nt < 4; ++nt)
        acc[ct][nt] = __builtin_amdgcn_mfma_f32_16x16x32_bf16(af[ct], bfr[nt], acc[ct][nt], 0, 0, 0);
  }

  // frag-ordered store: slice sl=r*8+b, head h=w
  u16* fragbase = fTf + (size_t)(((r * Bsz + b) * 4 + w) * 128) * 512;
#pragma unroll
  for (int ct = 0; ct < 4; ++ct) {
#pragma unroll
    for (int ntf = 0; ntf < 4; ++ntf) {
      const int j = n0 + ntf * 16 + m;
      const int jb = j >> 5;
      const int qt = ((ntf & 1) << 1) | (m >> 3);
      const int e = m & 7;
      u16* dst = fragbase + (size_t)((jb * 4 + ct) * 512) + (qt * 16 + quad * 4) * 8 + e;
#pragma unroll
      for (int p = 0; p < 4; ++p) dst[p * 8] = (u16)f2bf(acc[ct][ntf][p]);
    }
  }
}

// ---------- attention: barrier-free MFMA streaming ----------
// grid 1024: bid&31 = comb (b=comb>>2, r=comb&3; XCD gets 4 slices -> L2),
// bid>>5 = itile (32 i rows). block 256 = 4 waves = 4 heads; wave handles
// 2 A-frags (32 i) x all 64 c of its head. No __syncthreads in main loop.
__global__ __launch_bounds__(256, 4)
void gatt_attn(const unsigned long long* __restrict__ adjm,
               const u16* __restrict__ fTf, const float* __restrict__ Lip,
               const float* __restrict__ Ljp, float* __restrict__ out) {
  __shared__ float ljs[4 * 1024];

  const int t = threadIdx.x;
  const int comb = blockIdx.x & 31;
  const int b = comb >> 2, r = comb & 3;
  const int i0 = (blockIdx.x >> 5) * 32;
  const int h = t >> 6, lane = t & 63;
  const int m = lane & 15, quad = lane >> 4;
  const int qo = quad * 8;

  {  // stage lj for all 4 heads (16KB), once
#pragma unroll
    for (int q = 0; q < 4; ++q) {
      const int s = q * 256 + t;
      const int hh = s >> 8, off = s & 255;
      ((float4*)ljs)[hh * 256 + off] =
          ((const float4*)(Ljp + ((size_t)((r * NH + hh) * Bsz + b)) * Nn))[off];
    }
  }
  __syncthreads();

  const float* lipb = Lip + ((size_t)((r * NH + h) * Bsz + b)) * Nn;
  const float li0 = lipb[i0 + m];
  const float li1 = lipb[i0 + 16 + m];
  const unsigned long long* amp0 = adjm + ((size_t)((b * Nn + i0 + m) * NR + r)) * 16;
  const unsigned long long* amp1 = adjm + ((size_t)((b * Nn + i0 + 16 + m) * NR + r)) * 16;
  const bf16x8* fp = (const bf16x8*)fTf + (size_t)(((r * Bsz + b) * 4 + h)) * 8192;
  const float* ljh = ljs + h * Nn;

  bf16x8 ones;
#pragma unroll
  for (int e = 0; e < 8; ++e) ones[e] = (short)0x3F80;

  f32x4 acc[2][4], den[2];
#pragma unroll
  for (int iw = 0; iw < 2; ++iw) {
    den[iw] = (f32x4){0.f, 0.f, 0.f, 0.f};
#pragma unroll
    for (int nt = 0; nt < 4; ++nt) acc[iw][nt] = (f32x4){0.f, 0.f, 0.f, 0.f};
  }

  for (int jq = 0; jq < 16; ++jq) {
    const uint2 mw0 = *(const uint2*)(amp0 + jq);
    const uint2 mw1 = *(const uint2*)(amp1 + jq);
#pragma unroll
    for (int half = 0; half < 2; ++half) {
      const int jb = jq * 2 + half;
      const unsigned mb0 = ((half ? mw0.y : mw0.x) >> qo) & 0xFFu;
      const unsigned mb1 = ((half ? mw1.y : mw1.x) >> qo) & 0xFFu;
      const float4 la = *(const float4*)(ljh + jb * 32 + qo);
      const float4 lb = *(const float4*)(ljh + jb * 32 + qo + 4);
      const float ljv[8] = {la.x, la.y, la.z, la.w, lb.x, lb.y, lb.z, lb.w};
      bf16x8 bfr[4];
#pragma unroll
      for (int nt = 0; nt < 4; ++nt) bfr[nt] = fp[(jb * 4 + nt) * 64 + lane];
#pragma unroll
      for (int iw = 0; iw < 2; ++iw) {
        const float liv = iw ? li1 : li0;
        const unsigned mb = iw ? mb1 : mb0;
        unsigned wm[8];
#pragma unroll
        for (int e = 0; e < 8; ++e) {
          const float s = liv + ljv[e];
          const float ls = fmaxf(s, 0.2f * s);
          const float wv = fast_exp2(ls);
          const int msk = ((int)(mb << (31 - e))) >> 31;  // v_bfe_i32: 0 / -1
          wm[e] = __float_as_uint(wv) & (unsigned)msk;
        }
        union { unsigned u[4]; bf16x8 v; } af;
#pragma unroll
        for (int k = 0; k < 4; ++k)
          af.u[k] = (wm[2 * k] >> 16) | (wm[2 * k + 1] & 0xFFFF0000u);
        den[iw] = __builtin_amdgcn_mfma_f32_16x16x32_bf16(af.v, ones, den[iw], 0, 0, 0);
#pragma unroll
        for (int nt = 0; nt < 4; ++nt)
          acc[iw][nt] = __builtin_amdgcn_mfma_f32_16x16x32_bf16(af.v, bfr[nt], acc[iw][nt], 0, 0, 0);
      }
    }
  }

  // den[iw][p] is the rowsum for i-row quad*4+p (same across cols) — no shuffle
#pragma unroll
  for (int iw = 0; iw < 2; ++iw) {
#pragma unroll
    for (int p = 0; p < 4; ++p) {
      const float inv = __builtin_amdgcn_rcpf(den[iw][p]);
      const int i = i0 + iw * 16 + quad * 4 + p;
      float* op = out + ((size_t)(b * Nn) + i) * COUT + h * 64 + m;
#pragma unroll
      for (int nt = 0; nt < 4; ++nt) atomicAdd(op + nt * 16, acc[iw][nt][p] * inv);
    }
  }
}

extern "C" void kernel_launch(void* const* d_in, const int* in_sizes, int n_in,
                              void* d_out, int out_size, void* d_ws, size_t ws_size,
                              hipStream_t stream) {
  const float* X = (const float*)d_in[0];
  const int4* adj4 = (const int4*)d_in[1];
  const float* W = (const float*)d_in[2];
  const float* a = (const float*)d_in[3];
  float* out = (float*)d_out;

  char* ws = (char*)d_ws;
  u16* fTf = (u16*)ws;
  float* Lip = (float*)(ws + OFF_LIP);
  float* Ljp = (float*)(ws + OFF_LJP);
  unsigned long long* adjm = (unsigned long long*)(ws + OFF_ADJM);
  u16* Xbf = (u16*)(ws + OFF_XBF);
  u16* WbfT = (u16*)(ws + OFF_WBFT);
  float* wa_l = (float*)(ws + OFF_WAL);
  float* wa_r = (float*)(ws + OFF_WAR);

  hipMemsetAsync(d_out, 0, (size_t)out_size * sizeof(float), stream);
  gatt_pack<<<dim3(32768), dim3(256), 0, stream>>>(adj4, adjm);
  gatt_xconv<<<dim3(1024), dim3(256), 0, stream>>>((const float4*)X, (int4*)Xbf);
  gatt_wtrans<<<dim3(32), dim3(256), 0, stream>>>(W, WbfT);
  gatt_wa<<<dim3(16), dim3(256), 0, stream>>>(W, a, wa_l, wa_r);
  gatt_logit<<<dim3(512), dim3(256), 0, stream>>>(X, (const float4*)wa_l,
                                                  (const float4*)wa_r, Lip, Ljp);
  gatt_fgemm<<<dim3(512), dim3(256), 0, stream>>>(Xbf, WbfT, fTf);
  gatt_attn<<<dim3(1024), dim3(256), 0, stream>>>(adjm, fTf, Lip, Ljp, out);
}

// Round 5
// 294.697 us; speedup vs baseline: 3.0157x; 1.0484x over previous
//
#include <hip/hip_runtime.h>
#include <math.h>

#define Bsz 8
#define Nn 1024
#define CIN 256
#define COUT 256
#define NR 4
#define NH 4

typedef unsigned short u16;
typedef __attribute__((ext_vector_type(8))) short bf16x8;
typedef __attribute__((ext_vector_type(4))) float f32x4;
typedef __attribute__((ext_vector_type(2))) float f32x2;

// ws layout (bytes):
//   fTf  : [sl=r*8+b][h][jb 0..31][nt 0..3][lane] bf16x8  16 MB @ 0
//   Lip  : [combo=r*4+h][b][n] f32 (li*log2e)   512K @ 16M
//   Ljp  : same                                  512K @ 16.5M
//   adjm : [b][i][r][16] u64                     4 MB @ 17M
//   Xbf  : [b*n][k] bf16                         4 MB @ 21M
//   WbfT : [r][c][k] bf16                        512K @ 25M
//   wa_l : [combo][k] f32                        16K  @ 25.5M
//   wa_r : [combo][k] f32                        16K  @ +16K
//   outr : [r][b][n][c] f32                      32 MB @ 26M
#define OFF_LIP (16u << 20)
#define OFF_LJP ((16u << 20) + (512u << 10))
#define OFF_ADJM (17u << 20)
#define OFF_XBF (21u << 20)
#define OFF_WBFT (25u << 20)
#define OFF_WAL ((25u << 20) + (512u << 10))
#define OFF_WAR ((25u << 20) + (528u << 10))
#define OFF_OUTR (26u << 20)

#define LOG2E 1.4426950408889634f

__device__ __forceinline__ short f2bf(float x) {
  union { float f; unsigned u; } v; v.f = x;
  unsigned r = (v.u + 0x7FFFu + ((v.u >> 16) & 1u)) >> 16;
  return (short)r;
}

__device__ __forceinline__ float fast_exp2(float x) {
#if __has_builtin(__builtin_amdgcn_exp2f)
  return __builtin_amdgcn_exp2f(x);
#else
  return exp2f(x);
#endif
}

__device__ __forceinline__ int sbfe1(unsigned v, int bit) {
#if __has_builtin(__builtin_amdgcn_sbfe)
  return __builtin_amdgcn_sbfe((int)v, bit, 1);
#else
  return ((int)(v << (31 - bit))) >> 31;
#endif
}

__device__ __forceinline__ unsigned perm_hi16(unsigned hi, unsigned lo) {
#if __has_builtin(__builtin_amdgcn_perm)
  return __builtin_amdgcn_perm(hi, lo, 0x07060302u);
#else
  return (lo >> 16) | (hi & 0xFFFF0000u);
#endif
}

// async global->LDS, 16B per lane
__device__ __forceinline__ void gl_lds16(const void* g, void* l) {
  __builtin_amdgcn_global_load_lds(
      (const __attribute__((address_space(1))) unsigned int*)(unsigned long long)g,
      (__attribute__((address_space(3))) unsigned int*)(unsigned int)(unsigned long long)l,
      16, 0, 0);
}

// ---------- adjacency pack ----------
__global__ __launch_bounds__(256, 8)
void gatt_pack(const int4* __restrict__ adj4, unsigned long long* __restrict__ adjm) {
  const int t = threadIdx.x;
  const int wid = blockIdx.x * 4 + (t >> 6);
  const int lane = t & 63;
  const int jw = wid & 15;
  const int i = (wid >> 4) & 1023;
  const int b = wid >> 14;
  const int j = jw * 64 + lane;
  const int4 av = adj4[(size_t)(b * Nn + i) * Nn + j];
  const unsigned long long b0 = __ballot(av.x != 0);
  const unsigned long long b1 = __ballot(av.y != 0);
  const unsigned long long b2 = __ballot(av.z != 0);
  const unsigned long long b3 = __ballot(av.w != 0);
  if (lane < 4) {
    unsigned long long v = (lane == 0) ? b0 : (lane == 1) ? b1 : (lane == 2) ? b2 : b3;
    adjm[((size_t)((b * Nn + i) * NR + lane)) * 16 + jw] = v;
  }
}

// ---------- prep: W->bf16 transposed (bid<32) OR wa tables (bid>=32) ----------
__global__ __launch_bounds__(256, 4)
void gatt_prep(const float* __restrict__ W, const float* __restrict__ a,
               u16* __restrict__ WbfT, float* __restrict__ wa_l,
               float* __restrict__ wa_r) {
  const int t = threadIdx.x;
  if (blockIdx.x < 32) {
    const int r = blockIdx.x >> 3, kc = blockIdx.x & 7;
    u16 pk[32];
#pragma unroll 8
    for (int kk = 0; kk < 32; ++kk)
      pk[kk] = (u16)f2bf(W[(size_t)r * 65536 + (size_t)(kc * 32 + kk) * COUT + t]);
    u16* dst = WbfT + (size_t)r * 65536 + (size_t)t * CIN + kc * 32;
#pragma unroll
    for (int q = 0; q < 4; ++q) *(int4*)(dst + q * 8) = *(int4*)(pk + q * 8);
  } else {
    const int cb = blockIdx.x - 32;
    const int r = cb >> 2, h = cb & 3;
    float sl = 0.f, sr = 0.f;
    const float* Wp = W + (size_t)r * 65536 + (size_t)t * COUT + h * 64;
    const float* ap = a + r * 512 + h * 128;
#pragma unroll 8
    for (int c = 0; c < 64; ++c) {
      const float wv = Wp[c];
      sl = fmaf(wv, ap[c], sl);
      sr = fmaf(wv, ap[64 + c], sr);
    }
    wa_l[(size_t)cb * CIN + t] = sl;
    wa_r[(size_t)cb * CIN + t] = sr;
  }
}

// ---------- logits (fp32, pre-scaled by log2e) + X->bf16 conversion ----------
__global__ __launch_bounds__(256, 4)
void gatt_logitx(const float* __restrict__ X, const float4* __restrict__ wal4,
                 const float4* __restrict__ war4, float* __restrict__ Lip,
                 float* __restrict__ Ljp, u16* __restrict__ Xbf) {
  __shared__ float Xs[16 * 260];
  const int t = threadIdx.x;
  const int row0 = blockIdx.x * 16;
  {
    const int il = t >> 4, kq = t & 15;
    const float4* xp = (const float4*)(X + (size_t)(row0 + il) * CIN + kq * 16);
    float4 v[4];
    u16 pk[16];
#pragma unroll
    for (int u = 0; u < 4; ++u) {
      v[u] = xp[u];
      pk[u * 4 + 0] = (u16)f2bf(v[u].x);
      pk[u * 4 + 1] = (u16)f2bf(v[u].y);
      pk[u * 4 + 2] = (u16)f2bf(v[u].z);
      pk[u * 4 + 3] = (u16)f2bf(v[u].w);
    }
    float4* dst = (float4*)(Xs + il * 260 + kq * 16);
#pragma unroll
    for (int u = 0; u < 4; ++u) dst[u] = v[u];
    u16* xb = Xbf + (size_t)(row0 + il) * CIN + kq * 16;
    *(int4*)xb = *(int4*)pk;
    *(int4*)(xb + 8) = *(int4*)(pk + 8);
  }
  __syncthreads();
  const int rl = t >> 4, combo = t & 15;
  float li = 0.f, lj = 0.f;
#pragma unroll 8
  for (int k4 = 0; k4 < 64; ++k4) {
    const float4 x4 = *(const float4*)(Xs + rl * 260 + k4 * 4);
    const float4 wl = wal4[combo * 64 + k4];
    const float4 wr = war4[combo * 64 + k4];
    li += x4.x * wl.x + x4.y * wl.y + x4.z * wl.z + x4.w * wl.w;
    lj += x4.x * wr.x + x4.y * wr.y + x4.z * wr.z + x4.w * wr.w;
  }
  const int g = row0 + rl, b = g >> 10, n = g & 1023;
  const size_t idx = ((size_t)(combo * Bsz + b)) * Nn + n;
  Lip[idx] = li * LOG2E;
  Ljp[idx] = lj * LOG2E;
}

// ---------- f GEMM via MFMA, frag-ordered output ----------
__global__ __launch_bounds__(256)
void gatt_fgemm(const u16* __restrict__ Xbf, const u16* __restrict__ WbfT,
                u16* __restrict__ fTf) {
  __shared__ u16 lds_w[8192];
  __shared__ u16 lds_x[2048];
  const int t = threadIdx.x;
  const int r = blockIdx.x & 3, b = (blockIdx.x >> 2) & 7, ntl = blockIdx.x >> 5;
  const int n0 = ntl * 64;
  const int g0 = b * Nn + n0;
  const int lane = t & 63, w = t >> 6;
  const int m = lane & 15, quad = lane >> 4;
  const int cw = w * 64;
  const int xq = quad ^ (m & 3);

  const u16* Wsrc = WbfT + (size_t)r * 65536;
  f32x4 acc[4][4];
#pragma unroll
  for (int ct = 0; ct < 4; ++ct)
#pragma unroll
    for (int nt = 0; nt < 4; ++nt) acc[ct][nt] = (f32x4){0.f, 0.f, 0.f, 0.f};

  for (int kc = 0; kc < 8; ++kc) {
    __syncthreads();
#pragma unroll
    for (int q = 0; q < 4; ++q) {
      const int s = q * 256 + t;
      const int c = s >> 2, ks = (s & 3) ^ (c & 3);
      gl_lds16(Wsrc + (size_t)c * CIN + kc * 32 + ks * 8, lds_w + s * 8);
    }
    {
      const int s = t;
      const int n = s >> 2, ks = (s & 3) ^ (n & 3);
      gl_lds16(Xbf + (size_t)(g0 + n) * CIN + kc * 32 + ks * 8, lds_x + s * 8);
    }
    __syncthreads();

    bf16x8 af[4], bfr[4];
#pragma unroll
    for (int ct = 0; ct < 4; ++ct)
      af[ct] = *(const bf16x8*)(lds_w + (cw + ct * 16 + m) * 32 + xq * 8);
#pragma unroll
    for (int nt = 0; nt < 4; ++nt)
      bfr[nt] = *(const bf16x8*)(lds_x + (nt * 16 + m) * 32 + xq * 8);
#pragma unroll
    for (int ct = 0; ct < 4; ++ct)
#pragma unroll
      for (int nt = 0; nt < 4; ++nt)
        acc[ct][nt] = __builtin_amdgcn_mfma_f32_16x16x32_bf16(af[ct], bfr[nt], acc[ct][nt], 0, 0, 0);
  }

  u16* fragbase = fTf + (size_t)(((r * Bsz + b) * 4 + w) * 128) * 512;
#pragma unroll
  for (int ct = 0; ct < 4; ++ct) {
#pragma unroll
    for (int ntf = 0; ntf < 4; ++ntf) {
      const int j = n0 + ntf * 16 + m;
      const int jb = j >> 5;
      const int qt = ((ntf & 1) << 1) | (m >> 3);
      const int e = m & 7;
      u16* dst = fragbase + (size_t)((jb * 4 + ct) * 512) + (qt * 16 + quad * 4) * 8 + e;
#pragma unroll
      for (int p = 0; p < 4; ++p) dst[p * 8] = (u16)f2bf(acc[ct][ntf][p]);
    }
  }
}

// ---------- attention: barrier-free MFMA streaming, pk-math w-gen ----------
// grid 1024: bid&31 = comb (b,r); bid>>5 = itile (32 i). block 256 = 4 head-waves.
// Writes per-r slice outr[r] with PLAIN stores (no atomics); reduce sums r.
__global__ __launch_bounds__(256, 4)
void gatt_attn(const unsigned long long* __restrict__ adjm,
               const u16* __restrict__ fTf, const float* __restrict__ Lip,
               const float* __restrict__ Ljp, float* __restrict__ outr) {
  __shared__ float ljs[4 * 1024];

  const int t = threadIdx.x;
  const int comb = blockIdx.x & 31;
  const int b = comb >> 2, r = comb & 3;
  const int i0 = (blockIdx.x >> 5) * 32;
  const int h = t >> 6, lane = t & 63;
  const int m = lane & 15, quad = lane >> 4;
  const int qo = quad * 8;

  {  // stage lj for all 4 heads (16KB), once
#pragma unroll
    for (int q = 0; q < 4; ++q) {
      const int s = q * 256 + t;
      const int hh = s >> 8, off = s & 255;
      ((float4*)ljs)[hh * 256 + off] =
          ((const float4*)(Ljp + ((size_t)((r * NH + hh) * Bsz + b)) * Nn))[off];
    }
  }
  __syncthreads();

  const float* lipb = Lip + ((size_t)((r * NH + h) * Bsz + b)) * Nn;
  const float li0 = lipb[i0 + m];
  const float li1 = lipb[i0 + 16 + m];
  const unsigned long long* amp0 = adjm + ((size_t)((b * Nn + i0 + m) * NR + r)) * 16;
  const unsigned long long* amp1 = adjm + ((size_t)((b * Nn + i0 + 16 + m) * NR + r)) * 16;
  const bf16x8* fp = (const bf16x8*)fTf + (size_t)(((r * Bsz + b) * 4 + h)) * 8192;
  const float* ljh = ljs + h * Nn;

  bf16x8 ones;
#pragma unroll
  for (int e = 0; e < 8; ++e) ones[e] = (short)0x3F80;

  f32x4 acc[2][4], den[2];
#pragma unroll
  for (int iw = 0; iw < 2; ++iw) {
    den[iw] = (f32x4){0.f, 0.f, 0.f, 0.f};
#pragma unroll
    for (int nt = 0; nt < 4; ++nt) acc[iw][nt] = (f32x4){0.f, 0.f, 0.f, 0.f};
  }

  for (int jq = 0; jq < 16; ++jq) {
    const uint2 mw0 = *(const uint2*)(amp0 + jq);
    const uint2 mw1 = *(const uint2*)(amp1 + jq);
#pragma unroll
    for (int half = 0; half < 2; ++half) {
      const int jb = jq * 2 + half;
      const unsigned w0 = half ? mw0.y : mw0.x;
      const unsigned w1 = half ? mw1.y : mw1.x;
      const f32x2* lj2p = (const f32x2*)(ljh + jb * 32 + qo);
      bf16x8 bfr[4];
#pragma unroll
      for (int nt = 0; nt < 4; ++nt) bfr[nt] = fp[(jb * 4 + nt) * 64 + lane];
#pragma unroll
      for (int iw = 0; iw < 2; ++iw) {
        const float liv = iw ? li1 : li0;
        const unsigned mb = (iw ? w1 : w0) >> qo;
        const f32x2 li2 = {liv, liv};
        unsigned afu[4];
#pragma unroll
        for (int pr = 0; pr < 4; ++pr) {
          const f32x2 s2 = li2 + lj2p[pr];          // v_pk_add_f32
          const f32x2 s02 = s2 * 0.2f;              // v_pk_mul_f32
          const float t0 = fmaxf(s2.x, s02.x);
          const float t1 = fmaxf(s2.y, s02.y);
          const unsigned e0 =
              __float_as_uint(fast_exp2(t0)) & (unsigned)sbfe1(mb, 2 * pr);
          const unsigned e1 =
              __float_as_uint(fast_exp2(t1)) & (unsigned)sbfe1(mb, 2 * pr + 1);
          afu[pr] = perm_hi16(e1, e0);              // v_perm_b32 pack
        }
        union { unsigned u[4]; bf16x8 v; } af;
        af.u[0] = afu[0]; af.u[1] = afu[1]; af.u[2] = afu[2]; af.u[3] = afu[3];
        den[iw] = __builtin_amdgcn_mfma_f32_16x16x32_bf16(af.v, ones, den[iw], 0, 0, 0);
#pragma unroll
        for (int nt = 0; nt < 4; ++nt)
          acc[iw][nt] = __builtin_amdgcn_mfma_f32_16x16x32_bf16(af.v, bfr[nt], acc[iw][nt], 0, 0, 0);
      }
    }
  }

#pragma unroll
  for (int iw = 0; iw < 2; ++iw) {
#pragma unroll
    for (int p = 0; p < 4; ++p) {
      const float inv = __builtin_amdgcn_rcpf(den[iw][p]);
      const int i = i0 + iw * 16 + quad * 4 + p;
      float* op = outr + (((size_t)(r * Bsz + b) * Nn) + i) * COUT + h * 64 + m;
#pragma unroll
      for (int nt = 0; nt < 4; ++nt) op[nt * 16] = acc[iw][nt][p] * inv;
    }
  }
}

// ---------- reduce over r: out = sum_r outr[r] ----------
__global__ __launch_bounds__(256, 8)
void gatt_reduce(const float4* __restrict__ outr4, float4* __restrict__ out4) {
  const int idx = blockIdx.x * 256 + threadIdx.x;
  float4 v0 = outr4[idx];
  float4 v1 = outr4[idx + 524288];
  float4 v2 = outr4[idx + 2 * 524288];
  float4 v3 = outr4[idx + 3 * 524288];
  out4[idx] = make_float4(v0.x + v1.x + v2.x + v3.x, v0.y + v1.y + v2.y + v3.y,
                          v0.z + v1.z + v2.z + v3.z, v0.w + v1.w + v2.w + v3.w);
}

extern "C" void kernel_launch(void* const* d_in, const int* in_sizes, int n_in,
                              void* d_out, int out_size, void* d_ws, size_t ws_size,
                              hipStream_t stream) {
  const float* X = (const float*)d_in[0];
  const int4* adj4 = (const int4*)d_in[1];
  const float* W = (const float*)d_in[2];
  const float* a = (const float*)d_in[3];
  float* out = (float*)d_out;

  char* ws = (char*)d_ws;
  u16* fTf = (u16*)ws;
  float* Lip = (float*)(ws + OFF_LIP);
  float* Ljp = (float*)(ws + OFF_LJP);
  unsigned long long* adjm = (unsigned long long*)(ws + OFF_ADJM);
  u16* Xbf = (u16*)(ws + OFF_XBF);
  u16* WbfT = (u16*)(ws + OFF_WBFT);
  float* wa_l = (float*)(ws + OFF_WAL);
  float* wa_r = (float*)(ws + OFF_WAR);
  float* outr = (float*)(ws + OFF_OUTR);

  gatt_pack<<<dim3(32768), dim3(256), 0, stream>>>(adj4, adjm);
  gatt_prep<<<dim3(48), dim3(256), 0, stream>>>(W, a, WbfT, wa_l, wa_r);
  gatt_logitx<<<dim3(512), dim3(256), 0, stream>>>(X, (const float4*)wa_l,
                                                   (const float4*)wa_r, Lip, Ljp, Xbf);
  gatt_fgemm<<<dim3(512), dim3(256), 0, stream>>>(Xbf, WbfT, fTf);
  gatt_attn<<<dim3(1024), dim3(256), 0, stream>>>(adjm, fTf, Lip, Ljp, outr);
  gatt_reduce<<<dim3(2048), dim3(256), 0, stream>>>((const float4*)outr, (float4*)out);
}